// Round 9
// baseline (1199.532 us; speedup 1.0000x reference)
//
#include <hip/hip_runtime.h>
#include <hip/hip_bf16.h>

#define NN 384
#define CC 128
#define HH 4
#define DHD 32
#define RR (NN*NN)
#define LN_EPS 1e-5f
#define QSC 0.25503487f          // (1/sqrt(32)) / ln(2)  -> logits in log2 domain
#define LOG2E 1.4426950408889634f
#define NB 3                     // b's per kernB block

typedef unsigned short u16;
typedef __bf16 bf16x8 __attribute__((ext_vector_type(8)));
typedef float f32x4 __attribute__((ext_vector_type(4)));
typedef unsigned short u16x8 __attribute__((ext_vector_type(8)));

__device__ __forceinline__ u16 f2bf(float f) {
    unsigned u = __float_as_uint(f);
    u += 0x7fffu + ((u >> 16) & 1u);        // RNE
    return (u16)(u >> 16);
}
__device__ __forceinline__ float bf2f(u16 s) { return __uint_as_float(((unsigned)s) << 16); }
__device__ __forceinline__ u16 f2h(float f) {
    _Float16 h = (_Float16)f;               // v_cvt_f16_f32 (RNE)
    return __builtin_bit_cast(u16, h);
}
__device__ __forceinline__ float h2f(u16 u) {
    return (float)__builtin_bit_cast(_Float16, u);  // v_cvt_f32_f16
}
__device__ __forceinline__ unsigned cvtpk(float lo, float hi) {
    unsigned r;
    asm("v_cvt_pk_bf16_f32 %0, %1, %2" : "=v"(r) : "v"(lo), "v"(hi));
    return r;
}

// ---------------------------------------------------------------------------
// Kernel W: one-shot converts — 5 weight matrices f32->bf16, mask int32->bf16.
// ---------------------------------------------------------------------------
__global__ __launch_bounds__(256) void kernW(
    const float* __restrict__ wq, const float* __restrict__ wk, const float* __restrict__ wv,
    const float* __restrict__ wg, const float* __restrict__ wo, const int* __restrict__ mask,
    u16* __restrict__ wqb, u16* __restrict__ wkb, u16* __restrict__ wvb,
    u16* __restrict__ wgb, u16* __restrict__ wob, u16* __restrict__ maskbf)
{
    const int idx = blockIdx.x*256 + threadIdx.x;
    if (idx < 5*16384) {
        const int which = idx >> 14, off = idx & 16383;
        const float* src = which==0?wq: which==1?wk: which==2?wv: which==3?wg: wo;
        u16* dst        = which==0?wqb: which==1?wkb: which==2?wvb: which==3?wgb: wob;
        dst[off] = f2bf(src[off]);
    } else {
        const int off = idx - 5*16384;
        if (off < RR) maskbf[off] = (mask[off] != 0) ? (u16)0x3F80 : (u16)0;
    }
}

// ---------------------------------------------------------------------------
// Kernel A: LayerNorm + q/k/v/gate projections + pair bias (fp16, log2 domain).
// q pre-scaled by QSC (softmax scale, log2 domain).
// ---------------------------------------------------------------------------
__global__ __launch_bounds__(256) void kernA(
    const float* __restrict__ pair, const float* __restrict__ ln_w, const float* __restrict__ ln_b,
    const float* __restrict__ w_bias,
    const u16* __restrict__ wqb, const u16* __restrict__ wkb,
    const u16* __restrict__ wvb, const u16* __restrict__ wgb,
    u16* __restrict__ qbuf, u16* __restrict__ kbuf, u16* __restrict__ vT, u16* __restrict__ gbuf,
    u16* __restrict__ biash)
{
    __shared__ __align__(16) u16 x_tile[64*128];   // bf16, pitch 256B, XOR-swizzled
    __shared__ __align__(16) u16 w_lds[128*128];   // bf16, pitch 256B, XOR-swizzled

    const int t = threadIdx.x;
    const int bid = blockIdx.x;
    const int base = bid * 64;
    const int b = base / NN;
    const int m0 = base % NN;

    // ---- LayerNorm: 4 lanes per row ----
    const int rl = t >> 2;
    const int lq = t & 3;
    const int grow = base + rl;
    float x[32];
    {
        const float* src = pair + (size_t)grow * CC + lq * 32;
        #pragma unroll
        for (int j = 0; j < 8; j++) {
            f32x4 v = *reinterpret_cast<const f32x4*>(src + j*4);
            #pragma unroll
            for (int e = 0; e < 4; e++) x[j*4+e] = v[e];
        }
    }
    float s = 0.f, sq = 0.f;
    #pragma unroll
    for (int j = 0; j < 32; j++) { s += x[j]; sq += x[j]*x[j]; }
    s  += __shfl_xor(s, 1);  s  += __shfl_xor(s, 2);
    sq += __shfl_xor(sq, 1); sq += __shfl_xor(sq, 2);
    const float mu = s * (1.f/128.f);
    const float rstd = rsqrtf(sq * (1.f/128.f) - mu*mu + LN_EPS);
    float pb[4] = {0.f,0.f,0.f,0.f};
    #pragma unroll
    for (int j = 0; j < 32; j++) {
        const int c = lq*32 + j;
        float xh = (x[j] - mu) * rstd * ln_w[c] + ln_b[c];
        x[j] = xh;
        #pragma unroll
        for (int h = 0; h < 4; h++) pb[h] += xh * w_bias[h*CC + c];
    }
    #pragma unroll
    for (int j8 = 0; j8 < 4; j8++) {
        u16x8 pk;
        #pragma unroll
        for (int e = 0; e < 8; e++) pk[e] = f2bf(x[j8*8 + e]);
        unsigned addr = (unsigned)(rl*256 + (lq*32 + j8*8)*2) ^ (unsigned)((rl & 7) << 4);
        *reinterpret_cast<u16x8*>(reinterpret_cast<char*>(x_tile) + addr) = pk;
    }
    // pair bias (fp16, log2-domain): bias2[h][q][k] = dot(xhat_k, w_bias[h]) * log2e
    #pragma unroll
    for (int h = 0; h < 4; h++) {
        float v = pb[h];
        v += __shfl_xor(v, 1); v += __shfl_xor(v, 2);
        if (lq == h) biash[h*RR + grow] = f2h(v * LOG2E);
    }

    const int wv = t >> 6;
    const int lane = t & 63;
    const int lc = lane & 15;
    const int kg = lane >> 4;

    bf16x8 afr[4];
    {
        const int rA = wv*16 + lc;
        #pragma unroll
        for (int kt = 0; kt < 4; kt++) {
            unsigned addr = (unsigned)(rA*256 + (kt*32 + kg*8)*2) ^ (unsigned)((rA & 7) << 4);
            afr[kt] = *reinterpret_cast<const bf16x8*>(reinterpret_cast<const char*>(x_tile) + addr);
        }
    }

    const u16* Ws[4] = {wqb, wkb, wvb, wgb};
    for (int wi = 0; wi < 4; wi++) {
        __syncthreads();
        const u16* W = Ws[wi];
        #pragma unroll
        for (int i = 0; i < 8; i++) {
            const int chunk = i*256 + t;
            const int row = chunk >> 4;
            const int colc = (chunk & 15) * 8;
            u16x8 pk = *reinterpret_cast<const u16x8*>(W + row*CC + colc);
            unsigned addr = (unsigned)(row*256 + colc*2) ^ (unsigned)((row & 7) << 4);
            *reinterpret_cast<u16x8*>(reinterpret_cast<char*>(w_lds) + addr) = pk;
        }
        __syncthreads();

        #pragma unroll
        for (int dt = 0; dt < 8; dt++) {
            f32x4 acc = {0.f, 0.f, 0.f, 0.f};
            const int rB = dt*16 + lc;
            #pragma unroll
            for (int kt = 0; kt < 4; kt++) {
                unsigned addr = (unsigned)(rB*256 + (kt*32 + kg*8)*2) ^ (unsigned)((rB & 7) << 4);
                bf16x8 bfr = *reinterpret_cast<const bf16x8*>(reinterpret_cast<const char*>(w_lds) + addr);
                acc = __builtin_amdgcn_mfma_f32_16x16x32_bf16(afr[kt], bfr, acc, 0, 0, 0);
            }
            if (wi == 2) {
                #pragma unroll
                for (int i = 0; i < 4; i++) {
                    const int m = m0 + wv*16 + kg*4 + i;
                    vT[(size_t)(b*CC + dt*16 + lc) * NN + m] = f2bf(acc[i]);
                }
            } else {
                u16* dst = (wi == 0) ? qbuf : (wi == 1) ? kbuf : gbuf;
                #pragma unroll
                for (int i = 0; i < 4; i++) {
                    float v = acc[i];
                    if (wi == 0) v *= QSC;                       // fold softmax scale (log2)
                    if (wi == 3) v = 1.f / (1.f + __expf(-v));   // sigmoid gate
                    dst[(size_t)(base + wv*16 + kg*4 + i) * CC + dt*16 + lc] = f2bf(v);
                }
            }
        }
    }
}

// ---------------------------------------------------------------------------
// Kernel B: attention, zero staging. Grid 768 = 6 qsplit x 128 bgroup (NB=3).
// Block = 4 INDEPENDENT waves (no barriers); wave owns 16 q-rows. Loops b
// outer, h inner (q/K/V/g lines touched 4h-consecutively -> single HBM fetch;
// only the 1.18MB fp16 bias table must stay L2-resident). K/V/bias/mask frags
// read directly from global (L2-served; natural MFMA gather layout). LDS =
// per-wave P chunk buffer only (5KB) -> ~6 blocks/CU, 24 waves/CU, grid fully
// co-resident in one dispatch round (machine-wide lockstep restored).
// ---------------------------------------------------------------------------
__global__ __launch_bounds__(256, 6) void kernB(
    const u16* __restrict__ qbuf, const u16* __restrict__ kbuf, const u16* __restrict__ vT,
    const u16* __restrict__ gbuf, const u16* __restrict__ biash,
    const u16* __restrict__ maskbf, u16* __restrict__ wagbuf)
{
    __shared__ __align__(16) u16 Plds[4*640];      // per-wave 1280B: PV chunks + epilogue tile

    const int t = threadIdx.x;
    const int w = t >> 6;
    const int lane = t & 63;
    const int lc = lane & 15;
    const int kg = lane >> 4;

    const int bid = blockIdx.x;
    const int qsplit = bid >> 7;       // 0..5  (slow: the 6 sharers of K/V(b) are == mod 8 -> co-XCD)
    const int bgroup = bid & 127;      // 0..127
    const int b0 = bgroup * NB;
    const int qt = qsplit*64 + w*16;   // wave's q-tile

    char* pw = reinterpret_cast<char*>(Plds) + w*1280;

    for (int j = 0; j < NB; j++) {
        const int b = b0 + j;
        for (int h = 0; h < HH; h++) {
            const bf16x8 aq = *reinterpret_cast<const bf16x8*>(
                qbuf + (size_t)(b*NN + qt + lc)*CC + h*DHD + kg*8);

            // S^T = mfma(K, Q) + bias  (K frags + fp16 bias direct from global/L2)
            f32x4 S[24];
            #pragma unroll
            for (int mt = 0; mt < 24; mt++) {
                const uint2 bu = *reinterpret_cast<const uint2*>(
                    biash + (size_t)h*RR + (size_t)(qt + lc)*NN + mt*16 + kg*4);
                f32x4 bv4;
                bv4[0] = h2f((u16)(bu.x & 0xFFFFu));
                bv4[1] = h2f((u16)(bu.x >> 16));
                bv4[2] = h2f((u16)(bu.y & 0xFFFFu));
                bv4[3] = h2f((u16)(bu.y >> 16));
                const bf16x8 kf = *reinterpret_cast<const bf16x8*>(
                    kbuf + (size_t)(b*NN + mt*16 + lc)*CC + h*DHD + kg*8);
                S[mt] = __builtin_amdgcn_mfma_f32_16x16x32_bf16(kf, aq, bv4, 0, 0, 0);
            }
            // P = exp2(l) * mask01 (no max-sub: |l| small in log2 domain), sum
            f32x4 sum4 = {0.f,0.f,0.f,0.f};
            #pragma unroll
            for (int mt = 0; mt < 24; mt++) {
                const uint2 mp = *reinterpret_cast<const uint2*>(
                    maskbf + (size_t)b*NN + mt*16 + kg*4);   // broadcast, L2-resident
                float m01[4];
                m01[0] = __uint_as_float(mp.x << 16);
                m01[1] = __uint_as_float(mp.x & 0xFFFF0000u);
                m01[2] = __uint_as_float(mp.y << 16);
                m01[3] = __uint_as_float(mp.y & 0xFFFF0000u);
                #pragma unroll
                for (int i = 0; i < 4; i++) {
                    float e = __builtin_exp2f(S[mt][i]) * m01[i];
                    S[mt][i] = e;
                    sum4[i] += e;
                }
            }
            float sums = (sum4[0] + sum4[1]) + (sum4[2] + sum4[3]);
            sums += __shfl_xor(sums, 16);
            sums += __shfl_xor(sums, 32);
            const float sinv = 1.f / sums;

            // PV over 12 chunks of 32 keys; P via cvt_pk -> per-wave LDS;
            // V frags direct from global vT (L2)
            f32x4 acc0 = {0.f,0.f,0.f,0.f}, acc1 = {0.f,0.f,0.f,0.f};
            #pragma unroll
            for (int kt = 0; kt < 12; kt++) {
                uint2 w0, w1;
                w0.x = cvtpk(S[2*kt][0],   S[2*kt][1]);
                w0.y = cvtpk(S[2*kt][2],   S[2*kt][3]);
                w1.x = cvtpk(S[2*kt+1][0], S[2*kt+1][1]);
                w1.y = cvtpk(S[2*kt+1][2], S[2*kt+1][3]);
                const unsigned swz = (unsigned)((lc & 3) << 4);
                *reinterpret_cast<uint2*>(pw + ((unsigned)(lc*64 + kg*8)      ^ swz)) = w0;
                *reinterpret_cast<uint2*>(pw + ((unsigned)(lc*64 + 32 + kg*8) ^ swz)) = w1;
                const bf16x8 ap = *reinterpret_cast<const bf16x8*>(
                    pw + ((unsigned)(lc*64 + kg*16) ^ swz));
                const bf16x8 bv0 = *reinterpret_cast<const bf16x8*>(
                    vT + (size_t)(b*CC + h*DHD + lc)*NN + kt*32 + kg*8);
                const bf16x8 bv1 = *reinterpret_cast<const bf16x8*>(
                    vT + (size_t)(b*CC + h*DHD + 16 + lc)*NN + kt*32 + kg*8);
                acc0 = __builtin_amdgcn_mfma_f32_16x16x32_bf16(ap, bv0, acc0, 0, 0, 0);
                acc1 = __builtin_amdgcn_mfma_f32_16x16x32_bf16(ap, bv1, acc1, 0, 0, 0);
            }
            // epilogue: normalize -> per-wave LDS tile [16 rows][32 cols], pitch 80B
            #pragma unroll
            for (int i = 0; i < 4; i++) {
                const float si = __shfl(sinv, 4*kg + i);
                const int r0 = 4*kg + i;
                *reinterpret_cast<u16*>(pw + r0*80 + lc*2)      = f2bf(acc0[i] * si);
                *reinterpret_cast<u16*>(pw + r0*80 + 32 + lc*2) = f2bf(acc1[i] * si);
            }
            // coalesced readback + gate + 16B stores
            {
                const int rrow = lane >> 2;
                const int ch = lane & 3;
                u16x8 pv8 = *reinterpret_cast<const u16x8*>(pw + rrow*80 + ch*16);
                const size_t grow_ = (size_t)(b*NN + qt + rrow);
                const int gcol = h*DHD + ch*8;
                u16x8 g8 = *reinterpret_cast<const u16x8*>(gbuf + grow_*CC + gcol);
                u16x8 o8;
                #pragma unroll
                for (int e = 0; e < 8; e++) o8[e] = f2bf(bf2f(pv8[e]) * bf2f(g8[e]));
                *reinterpret_cast<u16x8*>(wagbuf + grow_*CC + gcol) = o8;
            }
        }
    }
}

// ---------------------------------------------------------------------------
// Kernel C: out = wag . w_o^T   (streaming GEMM, grid 2304 x 256)
// ---------------------------------------------------------------------------
__global__ __launch_bounds__(256) void kernC(
    const u16* __restrict__ wag, const u16* __restrict__ wob, float* __restrict__ out)
{
    __shared__ __align__(16) u16 a_tile[64*128];

    const int t = threadIdx.x;
    const int base = blockIdx.x * 64;

    {
        const int rl = t >> 2;
        const int lq = t & 3;
        const u16* src = wag + (size_t)(base + rl)*CC + lq*32;
        #pragma unroll
        for (int j8 = 0; j8 < 4; j8++) {
            u16x8 v = *reinterpret_cast<const u16x8*>(src + j8*8);
            unsigned addr = (unsigned)(rl*256 + (lq*32 + j8*8)*2) ^ (unsigned)((rl & 7) << 4);
            *reinterpret_cast<u16x8*>(reinterpret_cast<char*>(a_tile) + addr) = v;
        }
    }
    __syncthreads();

    const int wv = t >> 6;
    const int lane = t & 63;
    const int lc = lane & 15;
    const int kg = lane >> 4;

    bf16x8 afr[4];
    {
        const int rA = wv*16 + lc;
        #pragma unroll
        for (int kt = 0; kt < 4; kt++) {
            unsigned addr = (unsigned)(rA*256 + (kt*32 + kg*8)*2) ^ (unsigned)((rA & 7) << 4);
            afr[kt] = *reinterpret_cast<const bf16x8*>(reinterpret_cast<const char*>(a_tile) + addr);
        }
    }
    #pragma unroll
    for (int et = 0; et < 8; et++) {
        f32x4 acc = {0.f,0.f,0.f,0.f};
        #pragma unroll
        for (int kt = 0; kt < 4; kt++) {
            const bf16x8 bw = *reinterpret_cast<const bf16x8*>(wob + (et*16 + lc)*CC + kt*32 + kg*8);
            acc = __builtin_amdgcn_mfma_f32_16x16x32_bf16(afr[kt], bw, acc, 0, 0, 0);
        }
        #pragma unroll
        for (int i = 0; i < 4; i++)
            out[(size_t)(base + wv*16 + kg*4 + i)*CC + et*16 + lc] = acc[i];
    }
}

extern "C" void kernel_launch(void* const* d_in, const int* in_sizes, int n_in,
                              void* d_out, int out_size, void* d_ws, size_t ws_size,
                              hipStream_t stream)
{
    const float* pair  = (const float*)d_in[0];
    const int*   mask  = (const int*)d_in[1];
    const float* ln_w  = (const float*)d_in[2];
    const float* ln_b  = (const float*)d_in[3];
    const float* w_bias= (const float*)d_in[4];
    const float* w_q   = (const float*)d_in[5];
    const float* w_k   = (const float*)d_in[6];
    const float* w_v   = (const float*)d_in[7];
    const float* w_g   = (const float*)d_in[8];
    const float* w_o   = (const float*)d_in[9];
    float* out = (float*)d_out;

    char* ws = (char*)d_ws;
    const size_t SZ = (size_t)RR * CC * 2;       // 37,748,736
    u16* qbuf = (u16*)(ws);
    u16* kbuf = (u16*)(ws + SZ);
    u16* vT   = (u16*)(ws + 2*SZ);
    u16* gbuf = (u16*)(ws + 3*SZ);
    u16* biash = (u16*)(ws + 4*SZ);                             // 4*RR*2 = 1,179,648
    char* p = ws + 4*SZ + (size_t)4*RR*2;
    u16* wob  = (u16*)(p);            p += (size_t)CC*CC*2;     // 32 KiB
    u16* wqb  = (u16*)(p);            p += (size_t)CC*CC*2;
    u16* wkb  = (u16*)(p);            p += (size_t)CC*CC*2;
    u16* wvb  = (u16*)(p);            p += (size_t)CC*CC*2;
    u16* wgb  = (u16*)(p);            p += (size_t)CC*CC*2;
    u16* maskbf = (u16*)(p);          p += (size_t)RR*2;        // 288 KiB
    const size_t used = (size_t)(p - ws);
    u16* wagbuf = (ws_size >= used + SZ) ? (u16*)(p) : qbuf;

    kernW<<<dim3(896), dim3(256), 0, stream>>>(w_q, w_k, w_v, w_g, w_o, mask,
        wqb, wkb, wvb, wgb, wob, maskbf);
    kernA<<<dim3(RR/64), dim3(256), 0, stream>>>(pair, ln_w, ln_b, w_bias,
        wqb, wkb, wvb, wgb, qbuf, kbuf, vT, gbuf, biash);
    kernB<<<dim3(768), dim3(256), 0, stream>>>(qbuf, kbuf, vT, gbuf, biash, maskbf, wagbuf);
    kernC<<<dim3(RR/64), dim3(256), 0, stream>>>(wagbuf, wob, out);
}

// Round 10
// 901.726 us; speedup vs baseline: 1.3303x; 1.3303x over previous
//
#include <hip/hip_runtime.h>
#include <hip/hip_bf16.h>

#define NN 384
#define CC 128
#define HH 4
#define DHD 32
#define RR (NN*NN)
#define LN_EPS 1e-5f
#define QSC 0.25503487f          // (1/sqrt(32)) / ln(2)  -> logits in log2 domain
#define LOG2E 1.4426950408889634f
#define NB 3                     // b's per kernB block

typedef unsigned short u16;
typedef __bf16 bf16x8 __attribute__((ext_vector_type(8)));
typedef float f32x4 __attribute__((ext_vector_type(4)));
typedef unsigned short u16x8 __attribute__((ext_vector_type(8)));

__device__ __forceinline__ u16 f2bf(float f) {
    unsigned u = __float_as_uint(f);
    u += 0x7fffu + ((u >> 16) & 1u);        // RNE
    return (u16)(u >> 16);
}
__device__ __forceinline__ float bf2f(u16 s) { return __uint_as_float(((unsigned)s) << 16); }
__device__ __forceinline__ u16 f2h(float f) {
    _Float16 h = (_Float16)f;               // v_cvt_f16_f32 (RNE)
    return __builtin_bit_cast(u16, h);
}
__device__ __forceinline__ float h2f(u16 u) {
    return (float)__builtin_bit_cast(_Float16, u);  // v_cvt_f32_f16
}
__device__ __forceinline__ unsigned cvtpk(float lo, float hi) {
    unsigned r;
    asm("v_cvt_pk_bf16_f32 %0, %1, %2" : "=v"(r) : "v"(lo), "v"(hi));
    return r;
}

// ---------------------------------------------------------------------------
// Kernel W: one-shot converts — 5 weight matrices f32->bf16, mask int32->bf16.
// ---------------------------------------------------------------------------
__global__ __launch_bounds__(256) void kernW(
    const float* __restrict__ wq, const float* __restrict__ wk, const float* __restrict__ wv,
    const float* __restrict__ wg, const float* __restrict__ wo, const int* __restrict__ mask,
    u16* __restrict__ wqb, u16* __restrict__ wkb, u16* __restrict__ wvb,
    u16* __restrict__ wgb, u16* __restrict__ wob, u16* __restrict__ maskbf)
{
    const int idx = blockIdx.x*256 + threadIdx.x;
    if (idx < 5*16384) {
        const int which = idx >> 14, off = idx & 16383;
        const float* src = which==0?wq: which==1?wk: which==2?wv: which==3?wg: wo;
        u16* dst        = which==0?wqb: which==1?wkb: which==2?wvb: which==3?wgb: wob;
        dst[off] = f2bf(src[off]);
    } else {
        const int off = idx - 5*16384;
        if (off < RR) maskbf[off] = (mask[off] != 0) ? (u16)0x3F80 : (u16)0;
    }
}

// ---------------------------------------------------------------------------
// Kernel A: LayerNorm + q/k/v/gate projections + pair bias (fp16, log2 domain).
// q pre-scaled by QSC (softmax scale, log2 domain).
// ---------------------------------------------------------------------------
__global__ __launch_bounds__(256) void kernA(
    const float* __restrict__ pair, const float* __restrict__ ln_w, const float* __restrict__ ln_b,
    const float* __restrict__ w_bias,
    const u16* __restrict__ wqb, const u16* __restrict__ wkb,
    const u16* __restrict__ wvb, const u16* __restrict__ wgb,
    u16* __restrict__ qbuf, u16* __restrict__ kbuf, u16* __restrict__ vT, u16* __restrict__ gbuf,
    u16* __restrict__ biash)
{
    __shared__ __align__(16) u16 x_tile[64*128];   // bf16, pitch 256B, XOR-swizzled
    __shared__ __align__(16) u16 w_lds[128*128];   // bf16, pitch 256B, XOR-swizzled

    const int t = threadIdx.x;
    const int bid = blockIdx.x;
    const int base = bid * 64;
    const int b = base / NN;
    const int m0 = base % NN;

    // ---- LayerNorm: 4 lanes per row ----
    const int rl = t >> 2;
    const int lq = t & 3;
    const int grow = base + rl;
    float x[32];
    {
        const float* src = pair + (size_t)grow * CC + lq * 32;
        #pragma unroll
        for (int j = 0; j < 8; j++) {
            f32x4 v = *reinterpret_cast<const f32x4*>(src + j*4);
            #pragma unroll
            for (int e = 0; e < 4; e++) x[j*4+e] = v[e];
        }
    }
    float s = 0.f, sq = 0.f;
    #pragma unroll
    for (int j = 0; j < 32; j++) { s += x[j]; sq += x[j]*x[j]; }
    s  += __shfl_xor(s, 1);  s  += __shfl_xor(s, 2);
    sq += __shfl_xor(sq, 1); sq += __shfl_xor(sq, 2);
    const float mu = s * (1.f/128.f);
    const float rstd = rsqrtf(sq * (1.f/128.f) - mu*mu + LN_EPS);
    float pb[4] = {0.f,0.f,0.f,0.f};
    #pragma unroll
    for (int j = 0; j < 32; j++) {
        const int c = lq*32 + j;
        float xh = (x[j] - mu) * rstd * ln_w[c] + ln_b[c];
        x[j] = xh;
        #pragma unroll
        for (int h = 0; h < 4; h++) pb[h] += xh * w_bias[h*CC + c];
    }
    #pragma unroll
    for (int j8 = 0; j8 < 4; j8++) {
        u16x8 pk;
        #pragma unroll
        for (int e = 0; e < 8; e++) pk[e] = f2bf(x[j8*8 + e]);
        unsigned addr = (unsigned)(rl*256 + (lq*32 + j8*8)*2) ^ (unsigned)((rl & 7) << 4);
        *reinterpret_cast<u16x8*>(reinterpret_cast<char*>(x_tile) + addr) = pk;
    }
    // pair bias (fp16, log2-domain): bias2[h][q][k] = dot(xhat_k, w_bias[h]) * log2e
    #pragma unroll
    for (int h = 0; h < 4; h++) {
        float v = pb[h];
        v += __shfl_xor(v, 1); v += __shfl_xor(v, 2);
        if (lq == h) biash[h*RR + grow] = f2h(v * LOG2E);
    }

    const int wv = t >> 6;
    const int lane = t & 63;
    const int lc = lane & 15;
    const int kg = lane >> 4;

    bf16x8 afr[4];
    {
        const int rA = wv*16 + lc;
        #pragma unroll
        for (int kt = 0; kt < 4; kt++) {
            unsigned addr = (unsigned)(rA*256 + (kt*32 + kg*8)*2) ^ (unsigned)((rA & 7) << 4);
            afr[kt] = *reinterpret_cast<const bf16x8*>(reinterpret_cast<const char*>(x_tile) + addr);
        }
    }

    const u16* Ws[4] = {wqb, wkb, wvb, wgb};
    for (int wi = 0; wi < 4; wi++) {
        __syncthreads();
        const u16* W = Ws[wi];
        #pragma unroll
        for (int i = 0; i < 8; i++) {
            const int chunk = i*256 + t;
            const int row = chunk >> 4;
            const int colc = (chunk & 15) * 8;
            u16x8 pk = *reinterpret_cast<const u16x8*>(W + row*CC + colc);
            unsigned addr = (unsigned)(row*256 + colc*2) ^ (unsigned)((row & 7) << 4);
            *reinterpret_cast<u16x8*>(reinterpret_cast<char*>(w_lds) + addr) = pk;
        }
        __syncthreads();

        #pragma unroll
        for (int dt = 0; dt < 8; dt++) {
            f32x4 acc = {0.f, 0.f, 0.f, 0.f};
            const int rB = dt*16 + lc;
            #pragma unroll
            for (int kt = 0; kt < 4; kt++) {
                unsigned addr = (unsigned)(rB*256 + (kt*32 + kg*8)*2) ^ (unsigned)((rB & 7) << 4);
                bf16x8 bfr = *reinterpret_cast<const bf16x8*>(reinterpret_cast<const char*>(w_lds) + addr);
                acc = __builtin_amdgcn_mfma_f32_16x16x32_bf16(afr[kt], bfr, acc, 0, 0, 0);
            }
            if (wi == 2) {
                #pragma unroll
                for (int i = 0; i < 4; i++) {
                    const int m = m0 + wv*16 + kg*4 + i;
                    vT[(size_t)(b*CC + dt*16 + lc) * NN + m] = f2bf(acc[i]);
                }
            } else {
                u16* dst = (wi == 0) ? qbuf : (wi == 1) ? kbuf : gbuf;
                #pragma unroll
                for (int i = 0; i < 4; i++) {
                    float v = acc[i];
                    if (wi == 0) v *= QSC;                       // fold softmax scale (log2)
                    if (wi == 3) v = 1.f / (1.f + __expf(-v));   // sigmoid gate
                    dst[(size_t)(base + wv*16 + kg*4 + i) * CC + dt*16 + lc] = f2bf(v);
                }
            }
        }
    }
}

// ---------------------------------------------------------------------------
// Kernel B: attention, zero staging. Grid 768 = 6 qsplit x 128 bgroup (NB=3).
// Block = 4 INDEPENDENT waves (no barriers); wave owns 16 q-rows. Loops b
// outer, h inner. K/V/bias/mask frags read directly from global (L2-served).
// LDS = per-wave P buffer only (5KB). launch_bounds(256,4): VGPR cap 128
// (round-5-proven: S[24] fits, no spill) -> 4 blocks/CU slots, 768-block grid
// fully co-resident in ONE dispatch round (machine-wide lockstep).
// ---------------------------------------------------------------------------
__global__ __launch_bounds__(256, 4) void kernB(
    const u16* __restrict__ qbuf, const u16* __restrict__ kbuf, const u16* __restrict__ vT,
    const u16* __restrict__ gbuf, const u16* __restrict__ biash,
    const u16* __restrict__ maskbf, u16* __restrict__ wagbuf)
{
    __shared__ __align__(16) u16 Plds[4*640];      // per-wave 1280B: PV chunks + epilogue tile

    const int t = threadIdx.x;
    const int w = t >> 6;
    const int lane = t & 63;
    const int lc = lane & 15;
    const int kg = lane >> 4;

    const int bid = blockIdx.x;
    const int qsplit = bid >> 7;       // 0..5  (slow: the 6 sharers of K/V(b) are == mod 8 -> co-XCD)
    const int bgroup = bid & 127;      // 0..127
    const int b0 = bgroup * NB;
    const int qt = qsplit*64 + w*16;   // wave's q-tile

    char* pw = reinterpret_cast<char*>(Plds) + w*1280;

    for (int j = 0; j < NB; j++) {
        const int b = b0 + j;
        for (int h = 0; h < HH; h++) {
            const bf16x8 aq = *reinterpret_cast<const bf16x8*>(
                qbuf + (size_t)(b*NN + qt + lc)*CC + h*DHD + kg*8);

            // S^T = mfma(K, Q) + bias  (K frags + fp16 bias direct from global/L2)
            f32x4 S[24];
            #pragma unroll
            for (int mt = 0; mt < 24; mt++) {
                const uint2 bu = *reinterpret_cast<const uint2*>(
                    biash + (size_t)h*RR + (size_t)(qt + lc)*NN + mt*16 + kg*4);
                f32x4 bv4;
                bv4[0] = h2f((u16)(bu.x & 0xFFFFu));
                bv4[1] = h2f((u16)(bu.x >> 16));
                bv4[2] = h2f((u16)(bu.y & 0xFFFFu));
                bv4[3] = h2f((u16)(bu.y >> 16));
                const bf16x8 kf = *reinterpret_cast<const bf16x8*>(
                    kbuf + (size_t)(b*NN + mt*16 + lc)*CC + h*DHD + kg*8);
                S[mt] = __builtin_amdgcn_mfma_f32_16x16x32_bf16(kf, aq, bv4, 0, 0, 0);
            }
            // P = exp2(l) * mask01 (no max-sub: |l| small in log2 domain), sum
            f32x4 sum4 = {0.f,0.f,0.f,0.f};
            #pragma unroll
            for (int mt = 0; mt < 24; mt++) {
                const uint2 mp = *reinterpret_cast<const uint2*>(
                    maskbf + (size_t)b*NN + mt*16 + kg*4);   // broadcast, L2-resident
                float m01[4];
                m01[0] = __uint_as_float(mp.x << 16);
                m01[1] = __uint_as_float(mp.x & 0xFFFF0000u);
                m01[2] = __uint_as_float(mp.y << 16);
                m01[3] = __uint_as_float(mp.y & 0xFFFF0000u);
                #pragma unroll
                for (int i = 0; i < 4; i++) {
                    float e = __builtin_exp2f(S[mt][i]) * m01[i];
                    S[mt][i] = e;
                    sum4[i] += e;
                }
            }
            float sums = (sum4[0] + sum4[1]) + (sum4[2] + sum4[3]);
            sums += __shfl_xor(sums, 16);
            sums += __shfl_xor(sums, 32);
            const float sinv = 1.f / sums;

            // PV over 12 chunks of 32 keys; P via cvt_pk -> per-wave LDS;
            // V frags direct from global vT (L2)
            f32x4 acc0 = {0.f,0.f,0.f,0.f}, acc1 = {0.f,0.f,0.f,0.f};
            #pragma unroll
            for (int kt = 0; kt < 12; kt++) {
                uint2 w0, w1;
                w0.x = cvtpk(S[2*kt][0],   S[2*kt][1]);
                w0.y = cvtpk(S[2*kt][2],   S[2*kt][3]);
                w1.x = cvtpk(S[2*kt+1][0], S[2*kt+1][1]);
                w1.y = cvtpk(S[2*kt+1][2], S[2*kt+1][3]);
                const unsigned swz = (unsigned)((lc & 3) << 4);
                *reinterpret_cast<uint2*>(pw + ((unsigned)(lc*64 + kg*8)      ^ swz)) = w0;
                *reinterpret_cast<uint2*>(pw + ((unsigned)(lc*64 + 32 + kg*8) ^ swz)) = w1;
                const bf16x8 ap = *reinterpret_cast<const bf16x8*>(
                    pw + ((unsigned)(lc*64 + kg*16) ^ swz));
                const bf16x8 bv0 = *reinterpret_cast<const bf16x8*>(
                    vT + (size_t)(b*CC + h*DHD + lc)*NN + kt*32 + kg*8);
                const bf16x8 bv1 = *reinterpret_cast<const bf16x8*>(
                    vT + (size_t)(b*CC + h*DHD + 16 + lc)*NN + kt*32 + kg*8);
                acc0 = __builtin_amdgcn_mfma_f32_16x16x32_bf16(ap, bv0, acc0, 0, 0, 0);
                acc1 = __builtin_amdgcn_mfma_f32_16x16x32_bf16(ap, bv1, acc1, 0, 0, 0);
            }
            // epilogue: normalize -> per-wave LDS tile [16 rows][32 cols], pitch 80B
            #pragma unroll
            for (int i = 0; i < 4; i++) {
                const float si = __shfl(sinv, 4*kg + i);
                const int r0 = 4*kg + i;
                *reinterpret_cast<u16*>(pw + r0*80 + lc*2)      = f2bf(acc0[i] * si);
                *reinterpret_cast<u16*>(pw + r0*80 + 32 + lc*2) = f2bf(acc1[i] * si);
            }
            // coalesced readback + gate + 16B stores
            {
                const int rrow = lane >> 2;
                const int ch = lane & 3;
                u16x8 pv8 = *reinterpret_cast<const u16x8*>(pw + rrow*80 + ch*16);
                const size_t grow_ = (size_t)(b*NN + qt + rrow);
                const int gcol = h*DHD + ch*8;
                u16x8 g8 = *reinterpret_cast<const u16x8*>(gbuf + grow_*CC + gcol);
                u16x8 o8;
                #pragma unroll
                for (int e = 0; e < 8; e++) o8[e] = f2bf(bf2f(pv8[e]) * bf2f(g8[e]));
                *reinterpret_cast<u16x8*>(wagbuf + grow_*CC + gcol) = o8;
            }
        }
    }
}

// ---------------------------------------------------------------------------
// Kernel C: out = wag . w_o^T   (streaming GEMM, grid 2304 x 256)
// ---------------------------------------------------------------------------
__global__ __launch_bounds__(256) void kernC(
    const u16* __restrict__ wag, const u16* __restrict__ wob, float* __restrict__ out)
{
    __shared__ __align__(16) u16 a_tile[64*128];

    const int t = threadIdx.x;
    const int base = blockIdx.x * 64;

    {
        const int rl = t >> 2;
        const int lq = t & 3;
        const u16* src = wag + (size_t)(base + rl)*CC + lq*32;
        #pragma unroll
        for (int j8 = 0; j8 < 4; j8++) {
            u16x8 v = *reinterpret_cast<const u16x8*>(src + j8*8);
            unsigned addr = (unsigned)(rl*256 + (lq*32 + j8*8)*2) ^ (unsigned)((rl & 7) << 4);
            *reinterpret_cast<u16x8*>(reinterpret_cast<char*>(a_tile) + addr) = v;
        }
    }
    __syncthreads();

    const int wv = t >> 6;
    const int lane = t & 63;
    const int lc = lane & 15;
    const int kg = lane >> 4;

    bf16x8 afr[4];
    {
        const int rA = wv*16 + lc;
        #pragma unroll
        for (int kt = 0; kt < 4; kt++) {
            unsigned addr = (unsigned)(rA*256 + (kt*32 + kg*8)*2) ^ (unsigned)((rA & 7) << 4);
            afr[kt] = *reinterpret_cast<const bf16x8*>(reinterpret_cast<const char*>(a_tile) + addr);
        }
    }
    #pragma unroll
    for (int et = 0; et < 8; et++) {
        f32x4 acc = {0.f,0.f,0.f,0.f};
        #pragma unroll
        for (int kt = 0; kt < 4; kt++) {
            const bf16x8 bw = *reinterpret_cast<const bf16x8*>(wob + (et*16 + lc)*CC + kt*32 + kg*8);
            acc = __builtin_amdgcn_mfma_f32_16x16x32_bf16(afr[kt], bw, acc, 0, 0, 0);
        }
        #pragma unroll
        for (int i = 0; i < 4; i++)
            out[(size_t)(base + wv*16 + kg*4 + i)*CC + et*16 + lc] = acc[i];
    }
}

extern "C" void kernel_launch(void* const* d_in, const int* in_sizes, int n_in,
                              void* d_out, int out_size, void* d_ws, size_t ws_size,
                              hipStream_t stream)
{
    const float* pair  = (const float*)d_in[0];
    const int*   mask  = (const int*)d_in[1];
    const float* ln_w  = (const float*)d_in[2];
    const float* ln_b  = (const float*)d_in[3];
    const float* w_bias= (const float*)d_in[4];
    const float* w_q   = (const float*)d_in[5];
    const float* w_k   = (const float*)d_in[6];
    const float* w_v   = (const float*)d_in[7];
    const float* w_g   = (const float*)d_in[8];
    const float* w_o   = (const float*)d_in[9];
    float* out = (float*)d_out;

    char* ws = (char*)d_ws;
    const size_t SZ = (size_t)RR * CC * 2;       // 37,748,736
    u16* qbuf = (u16*)(ws);
    u16* kbuf = (u16*)(ws + SZ);
    u16* vT   = (u16*)(ws + 2*SZ);
    u16* gbuf = (u16*)(ws + 3*SZ);
    u16* biash = (u16*)(ws + 4*SZ);                             // 4*RR*2 = 1,179,648
    char* p = ws + 4*SZ + (size_t)4*RR*2;
    u16* wob  = (u16*)(p);            p += (size_t)CC*CC*2;     // 32 KiB
    u16* wqb  = (u16*)(p);            p += (size_t)CC*CC*2;
    u16* wkb  = (u16*)(p);            p += (size_t)CC*CC*2;
    u16* wvb  = (u16*)(p);            p += (size_t)CC*CC*2;
    u16* wgb  = (u16*)(p);            p += (size_t)CC*CC*2;
    u16* maskbf = (u16*)(p);          p += (size_t)RR*2;        // 288 KiB
    const size_t used = (size_t)(p - ws);
    u16* wagbuf = (ws_size >= used + SZ) ? (u16*)(p) : qbuf;

    kernW<<<dim3(896), dim3(256), 0, stream>>>(w_q, w_k, w_v, w_g, w_o, mask,
        wqb, wkb, wvb, wgb, wob, maskbf);
    kernA<<<dim3(RR/64), dim3(256), 0, stream>>>(pair, ln_w, ln_b, w_bias,
        wqb, wkb, wvb, wgb, qbuf, kbuf, vT, gbuf, biash);
    kernB<<<dim3(768), dim3(256), 0, stream>>>(qbuf, kbuf, vT, gbuf, biash, maskbf, wagbuf);
    kernC<<<dim3(RR/64), dim3(256), 0, stream>>>(wagbuf, wob, out);
}

// Round 11
// 850.671 us; speedup vs baseline: 1.4101x; 1.0600x over previous
//
#include <hip/hip_runtime.h>
#include <hip/hip_bf16.h>

#define NN 384
#define CC 128
#define HH 4
#define DHD 32
#define RR (NN*NN)
#define LN_EPS 1e-5f
#define QSC 0.25503487f          // (1/sqrt(32)) / ln(2)  -> logits in log2 domain
#define LOG2E 1.4426950408889634f
#define NB 3                     // b's per kernB block

typedef unsigned short u16;
typedef __bf16 bf16x8 __attribute__((ext_vector_type(8)));
typedef float f32x4 __attribute__((ext_vector_type(4)));
typedef unsigned short u16x8 __attribute__((ext_vector_type(8)));

__device__ __forceinline__ u16 f2bf(float f) {
    unsigned u = __float_as_uint(f);
    u += 0x7fffu + ((u >> 16) & 1u);        // RNE
    return (u16)(u >> 16);
}
__device__ __forceinline__ float bf2f(u16 s) { return __uint_as_float(((unsigned)s) << 16); }
__device__ __forceinline__ u16 f2h(float f) {
    _Float16 h = (_Float16)f;               // v_cvt_f16_f32 (RNE)
    return __builtin_bit_cast(u16, h);
}
__device__ __forceinline__ float h2f(u16 u) {
    return (float)__builtin_bit_cast(_Float16, u);  // v_cvt_f32_f16
}
__device__ __forceinline__ unsigned cvtpk(float lo, float hi) {
    unsigned r;
    asm("v_cvt_pk_bf16_f32 %0, %1, %2" : "=v"(r) : "v"(lo), "v"(hi));
    return r;
}

// ---------------------------------------------------------------------------
// Kernel W: one-shot converts — 5 weight matrices f32->bf16, mask int32->bf16.
// ---------------------------------------------------------------------------
__global__ __launch_bounds__(256) void kernW(
    const float* __restrict__ wq, const float* __restrict__ wk, const float* __restrict__ wv,
    const float* __restrict__ wg, const float* __restrict__ wo, const int* __restrict__ mask,
    u16* __restrict__ wqb, u16* __restrict__ wkb, u16* __restrict__ wvb,
    u16* __restrict__ wgb, u16* __restrict__ wob, u16* __restrict__ maskbf)
{
    const int idx = blockIdx.x*256 + threadIdx.x;
    if (idx < 5*16384) {
        const int which = idx >> 14, off = idx & 16383;
        const float* src = which==0?wq: which==1?wk: which==2?wv: which==3?wg: wo;
        u16* dst        = which==0?wqb: which==1?wkb: which==2?wvb: which==3?wgb: wob;
        dst[off] = f2bf(src[off]);
    } else {
        const int off = idx - 5*16384;
        if (off < RR) maskbf[off] = (mask[off] != 0) ? (u16)0x3F80 : (u16)0;
    }
}

// ---------------------------------------------------------------------------
// Kernel A: LayerNorm + q/k/v/gate projections + pair bias (fp16, log2 domain).
// q pre-scaled by QSC (softmax scale, log2 domain).
// ---------------------------------------------------------------------------
__global__ __launch_bounds__(256) void kernA(
    const float* __restrict__ pair, const float* __restrict__ ln_w, const float* __restrict__ ln_b,
    const float* __restrict__ w_bias,
    const u16* __restrict__ wqb, const u16* __restrict__ wkb,
    const u16* __restrict__ wvb, const u16* __restrict__ wgb,
    u16* __restrict__ qbuf, u16* __restrict__ kbuf, u16* __restrict__ vT, u16* __restrict__ gbuf,
    u16* __restrict__ biash)
{
    __shared__ __align__(16) u16 x_tile[64*128];   // bf16, pitch 256B, XOR-swizzled
    __shared__ __align__(16) u16 w_lds[128*128];   // bf16, pitch 256B, XOR-swizzled

    const int t = threadIdx.x;
    const int bid = blockIdx.x;
    const int base = bid * 64;
    const int b = base / NN;
    const int m0 = base % NN;

    // ---- LayerNorm: 4 lanes per row ----
    const int rl = t >> 2;
    const int lq = t & 3;
    const int grow = base + rl;
    float x[32];
    {
        const float* src = pair + (size_t)grow * CC + lq * 32;
        #pragma unroll
        for (int j = 0; j < 8; j++) {
            f32x4 v = *reinterpret_cast<const f32x4*>(src + j*4);
            #pragma unroll
            for (int e = 0; e < 4; e++) x[j*4+e] = v[e];
        }
    }
    float s = 0.f, sq = 0.f;
    #pragma unroll
    for (int j = 0; j < 32; j++) { s += x[j]; sq += x[j]*x[j]; }
    s  += __shfl_xor(s, 1);  s  += __shfl_xor(s, 2);
    sq += __shfl_xor(sq, 1); sq += __shfl_xor(sq, 2);
    const float mu = s * (1.f/128.f);
    const float rstd = rsqrtf(sq * (1.f/128.f) - mu*mu + LN_EPS);
    float pb[4] = {0.f,0.f,0.f,0.f};
    #pragma unroll
    for (int j = 0; j < 32; j++) {
        const int c = lq*32 + j;
        float xh = (x[j] - mu) * rstd * ln_w[c] + ln_b[c];
        x[j] = xh;
        #pragma unroll
        for (int h = 0; h < 4; h++) pb[h] += xh * w_bias[h*CC + c];
    }
    #pragma unroll
    for (int j8 = 0; j8 < 4; j8++) {
        u16x8 pk;
        #pragma unroll
        for (int e = 0; e < 8; e++) pk[e] = f2bf(x[j8*8 + e]);
        unsigned addr = (unsigned)(rl*256 + (lq*32 + j8*8)*2) ^ (unsigned)((rl & 7) << 4);
        *reinterpret_cast<u16x8*>(reinterpret_cast<char*>(x_tile) + addr) = pk;
    }
    // pair bias (fp16, log2-domain): bias2[h][q][k] = dot(xhat_k, w_bias[h]) * log2e
    #pragma unroll
    for (int h = 0; h < 4; h++) {
        float v = pb[h];
        v += __shfl_xor(v, 1); v += __shfl_xor(v, 2);
        if (lq == h) biash[h*RR + grow] = f2h(v * LOG2E);
    }

    const int wv = t >> 6;
    const int lane = t & 63;
    const int lc = lane & 15;
    const int kg = lane >> 4;

    bf16x8 afr[4];
    {
        const int rA = wv*16 + lc;
        #pragma unroll
        for (int kt = 0; kt < 4; kt++) {
            unsigned addr = (unsigned)(rA*256 + (kt*32 + kg*8)*2) ^ (unsigned)((rA & 7) << 4);
            afr[kt] = *reinterpret_cast<const bf16x8*>(reinterpret_cast<const char*>(x_tile) + addr);
        }
    }

    const u16* Ws[4] = {wqb, wkb, wvb, wgb};
    for (int wi = 0; wi < 4; wi++) {
        __syncthreads();
        const u16* W = Ws[wi];
        #pragma unroll
        for (int i = 0; i < 8; i++) {
            const int chunk = i*256 + t;
            const int row = chunk >> 4;
            const int colc = (chunk & 15) * 8;
            u16x8 pk = *reinterpret_cast<const u16x8*>(W + row*CC + colc);
            unsigned addr = (unsigned)(row*256 + colc*2) ^ (unsigned)((row & 7) << 4);
            *reinterpret_cast<u16x8*>(reinterpret_cast<char*>(w_lds) + addr) = pk;
        }
        __syncthreads();

        #pragma unroll
        for (int dt = 0; dt < 8; dt++) {
            f32x4 acc = {0.f, 0.f, 0.f, 0.f};
            const int rB = dt*16 + lc;
            #pragma unroll
            for (int kt = 0; kt < 4; kt++) {
                unsigned addr = (unsigned)(rB*256 + (kt*32 + kg*8)*2) ^ (unsigned)((rB & 7) << 4);
                bf16x8 bfr = *reinterpret_cast<const bf16x8*>(reinterpret_cast<const char*>(w_lds) + addr);
                acc = __builtin_amdgcn_mfma_f32_16x16x32_bf16(afr[kt], bfr, acc, 0, 0, 0);
            }
            if (wi == 2) {
                #pragma unroll
                for (int i = 0; i < 4; i++) {
                    const int m = m0 + wv*16 + kg*4 + i;
                    vT[(size_t)(b*CC + dt*16 + lc) * NN + m] = f2bf(acc[i]);
                }
            } else {
                u16* dst = (wi == 0) ? qbuf : (wi == 1) ? kbuf : gbuf;
                #pragma unroll
                for (int i = 0; i < 4; i++) {
                    float v = acc[i];
                    if (wi == 0) v *= QSC;                       // fold softmax scale (log2)
                    if (wi == 3) v = 1.f / (1.f + __expf(-v));   // sigmoid gate
                    dst[(size_t)(base + wv*16 + kg*4 + i) * CC + dt*16 + lc] = f2bf(v);
                }
            }
        }
    }
}

// ---------------------------------------------------------------------------
// Kernel B: attention, zero staging. Grid 768 = 6 qsplit x 128 bgroup (NB=3).
// Block = 4 INDEPENDENT waves (no barriers); wave owns 16 q-rows. Loops b
// outer, h inner. K/V/bias/mask frags read directly from global (L2-served).
// LDS = per-wave P buffer only (5KB).
// amdgpu_waves_per_eu(3,4): min 3 waves/EU -> VGPR cap 170 (S[24]+temps
// ~140 fits, NO SPILL); max 4 stops LLVM's occupancy heuristic from
// squeezing to 64-80 VGPR and spilling S (the r6-r10 failure mode).
// Either outcome (3 or 4 blocks/CU) keeps the 768-block grid fully
// co-resident in one dispatch round.
// ---------------------------------------------------------------------------
__global__ __launch_bounds__(256) __attribute__((amdgpu_waves_per_eu(3, 4))) void kernB(
    const u16* __restrict__ qbuf, const u16* __restrict__ kbuf, const u16* __restrict__ vT,
    const u16* __restrict__ gbuf, const u16* __restrict__ biash,
    const u16* __restrict__ maskbf, u16* __restrict__ wagbuf)
{
    __shared__ __align__(16) u16 Plds[4*640];      // per-wave 1280B: PV chunks + epilogue tile

    const int t = threadIdx.x;
    const int w = t >> 6;
    const int lane = t & 63;
    const int lc = lane & 15;
    const int kg = lane >> 4;

    const int bid = blockIdx.x;
    const int qsplit = bid >> 7;       // 0..5  (slow: the 6 sharers of K/V(b) are == mod 8 -> co-XCD)
    const int bgroup = bid & 127;      // 0..127
    const int b0 = bgroup * NB;
    const int qt = qsplit*64 + w*16;   // wave's q-tile

    char* pw = reinterpret_cast<char*>(Plds) + w*1280;

    for (int j = 0; j < NB; j++) {
        const int b = b0 + j;
        for (int h = 0; h < HH; h++) {
            const bf16x8 aq = *reinterpret_cast<const bf16x8*>(
                qbuf + (size_t)(b*NN + qt + lc)*CC + h*DHD + kg*8);

            // S^T = mfma(K, Q) + bias  (K frags + fp16 bias direct from global/L2)
            f32x4 S[24];
            #pragma unroll
            for (int mt = 0; mt < 24; mt++) {
                const uint2 bu = *reinterpret_cast<const uint2*>(
                    biash + (size_t)h*RR + (size_t)(qt + lc)*NN + mt*16 + kg*4);
                f32x4 bv4;
                bv4[0] = h2f((u16)(bu.x & 0xFFFFu));
                bv4[1] = h2f((u16)(bu.x >> 16));
                bv4[2] = h2f((u16)(bu.y & 0xFFFFu));
                bv4[3] = h2f((u16)(bu.y >> 16));
                const bf16x8 kf = *reinterpret_cast<const bf16x8*>(
                    kbuf + (size_t)(b*NN + mt*16 + lc)*CC + h*DHD + kg*8);
                S[mt] = __builtin_amdgcn_mfma_f32_16x16x32_bf16(kf, aq, bv4, 0, 0, 0);
            }
            // P = exp2(l) * mask01 (no max-sub: |l| small in log2 domain), sum
            f32x4 sum4 = {0.f,0.f,0.f,0.f};
            #pragma unroll
            for (int mt = 0; mt < 24; mt++) {
                const uint2 mp = *reinterpret_cast<const uint2*>(
                    maskbf + (size_t)b*NN + mt*16 + kg*4);   // broadcast, L2-resident
                float m01[4];
                m01[0] = __uint_as_float(mp.x << 16);
                m01[1] = __uint_as_float(mp.x & 0xFFFF0000u);
                m01[2] = __uint_as_float(mp.y << 16);
                m01[3] = __uint_as_float(mp.y & 0xFFFF0000u);
                #pragma unroll
                for (int i = 0; i < 4; i++) {
                    float e = __builtin_exp2f(S[mt][i]) * m01[i];
                    S[mt][i] = e;
                    sum4[i] += e;
                }
            }
            float sums = (sum4[0] + sum4[1]) + (sum4[2] + sum4[3]);
            sums += __shfl_xor(sums, 16);
            sums += __shfl_xor(sums, 32);
            const float sinv = 1.f / sums;

            // PV over 12 chunks of 32 keys; P via cvt_pk -> per-wave LDS;
            // V frags direct from global vT (L2)
            f32x4 acc0 = {0.f,0.f,0.f,0.f}, acc1 = {0.f,0.f,0.f,0.f};
            #pragma unroll
            for (int kt = 0; kt < 12; kt++) {
                uint2 w0, w1;
                w0.x = cvtpk(S[2*kt][0],   S[2*kt][1]);
                w0.y = cvtpk(S[2*kt][2],   S[2*kt][3]);
                w1.x = cvtpk(S[2*kt+1][0], S[2*kt+1][1]);
                w1.y = cvtpk(S[2*kt+1][2], S[2*kt+1][3]);
                const unsigned swz = (unsigned)((lc & 3) << 4);
                *reinterpret_cast<uint2*>(pw + ((unsigned)(lc*64 + kg*8)      ^ swz)) = w0;
                *reinterpret_cast<uint2*>(pw + ((unsigned)(lc*64 + 32 + kg*8) ^ swz)) = w1;
                const bf16x8 ap = *reinterpret_cast<const bf16x8*>(
                    pw + ((unsigned)(lc*64 + kg*16) ^ swz));
                const bf16x8 bv0 = *reinterpret_cast<const bf16x8*>(
                    vT + (size_t)(b*CC + h*DHD + lc)*NN + kt*32 + kg*8);
                const bf16x8 bv1 = *reinterpret_cast<const bf16x8*>(
                    vT + (size_t)(b*CC + h*DHD + 16 + lc)*NN + kt*32 + kg*8);
                acc0 = __builtin_amdgcn_mfma_f32_16x16x32_bf16(ap, bv0, acc0, 0, 0, 0);
                acc1 = __builtin_amdgcn_mfma_f32_16x16x32_bf16(ap, bv1, acc1, 0, 0, 0);
            }
            // epilogue: normalize -> per-wave LDS tile [16 rows][32 cols], pitch 80B
            #pragma unroll
            for (int i = 0; i < 4; i++) {
                const float si = __shfl(sinv, 4*kg + i);
                const int r0 = 4*kg + i;
                *reinterpret_cast<u16*>(pw + r0*80 + lc*2)      = f2bf(acc0[i] * si);
                *reinterpret_cast<u16*>(pw + r0*80 + 32 + lc*2) = f2bf(acc1[i] * si);
            }
            // coalesced readback + gate + 16B stores
            {
                const int rrow = lane >> 2;
                const int ch = lane & 3;
                u16x8 pv8 = *reinterpret_cast<const u16x8*>(pw + rrow*80 + ch*16);
                const size_t grow_ = (size_t)(b*NN + qt + rrow);
                const int gcol = h*DHD + ch*8;
                u16x8 g8 = *reinterpret_cast<const u16x8*>(gbuf + grow_*CC + gcol);
                u16x8 o8;
                #pragma unroll
                for (int e = 0; e < 8; e++) o8[e] = f2bf(bf2f(pv8[e]) * bf2f(g8[e]));
                *reinterpret_cast<u16x8*>(wagbuf + grow_*CC + gcol) = o8;
            }
        }
    }
}

// ---------------------------------------------------------------------------
// Kernel C: out = wag . w_o^T   (streaming GEMM, grid 2304 x 256)
// ---------------------------------------------------------------------------
__global__ __launch_bounds__(256) void kernC(
    const u16* __restrict__ wag, const u16* __restrict__ wob, float* __restrict__ out)
{
    __shared__ __align__(16) u16 a_tile[64*128];

    const int t = threadIdx.x;
    const int base = blockIdx.x * 64;

    {
        const int rl = t >> 2;
        const int lq = t & 3;
        const u16* src = wag + (size_t)(base + rl)*CC + lq*32;
        #pragma unroll
        for (int j8 = 0; j8 < 4; j8++) {
            u16x8 v = *reinterpret_cast<const u16x8*>(src + j8*8);
            unsigned addr = (unsigned)(rl*256 + (lq*32 + j8*8)*2) ^ (unsigned)((rl & 7) << 4);
            *reinterpret_cast<u16x8*>(reinterpret_cast<char*>(a_tile) + addr) = v;
        }
    }
    __syncthreads();

    const int wv = t >> 6;
    const int lane = t & 63;
    const int lc = lane & 15;
    const int kg = lane >> 4;

    bf16x8 afr[4];
    {
        const int rA = wv*16 + lc;
        #pragma unroll
        for (int kt = 0; kt < 4; kt++) {
            unsigned addr = (unsigned)(rA*256 + (kt*32 + kg*8)*2) ^ (unsigned)((rA & 7) << 4);
            afr[kt] = *reinterpret_cast<const bf16x8*>(reinterpret_cast<const char*>(a_tile) + addr);
        }
    }
    #pragma unroll
    for (int et = 0; et < 8; et++) {
        f32x4 acc = {0.f,0.f,0.f,0.f};
        #pragma unroll
        for (int kt = 0; kt < 4; kt++) {
            const bf16x8 bw = *reinterpret_cast<const bf16x8*>(wob + (et*16 + lc)*CC + kt*32 + kg*8);
            acc = __builtin_amdgcn_mfma_f32_16x16x32_bf16(afr[kt], bw, acc, 0, 0, 0);
        }
        #pragma unroll
        for (int i = 0; i < 4; i++)
            out[(size_t)(base + wv*16 + kg*4 + i)*CC + et*16 + lc] = acc[i];
    }
}

extern "C" void kernel_launch(void* const* d_in, const int* in_sizes, int n_in,
                              void* d_out, int out_size, void* d_ws, size_t ws_size,
                              hipStream_t stream)
{
    const float* pair  = (const float*)d_in[0];
    const int*   mask  = (const int*)d_in[1];
    const float* ln_w  = (const float*)d_in[2];
    const float* ln_b  = (const float*)d_in[3];
    const float* w_bias= (const float*)d_in[4];
    const float* w_q   = (const float*)d_in[5];
    const float* w_k   = (const float*)d_in[6];
    const float* w_v   = (const float*)d_in[7];
    const float* w_g   = (const float*)d_in[8];
    const float* w_o   = (const float*)d_in[9];
    float* out = (float*)d_out;

    char* ws = (char*)d_ws;
    const size_t SZ = (size_t)RR * CC * 2;       // 37,748,736
    u16* qbuf = (u16*)(ws);
    u16* kbuf = (u16*)(ws + SZ);
    u16* vT   = (u16*)(ws + 2*SZ);
    u16* gbuf = (u16*)(ws + 3*SZ);
    u16* biash = (u16*)(ws + 4*SZ);                             // 4*RR*2 = 1,179,648
    char* p = ws + 4*SZ + (size_t)4*RR*2;
    u16* wob  = (u16*)(p);            p += (size_t)CC*CC*2;     // 32 KiB
    u16* wqb  = (u16*)(p);            p += (size_t)CC*CC*2;
    u16* wkb  = (u16*)(p);            p += (size_t)CC*CC*2;
    u16* wvb  = (u16*)(p);            p += (size_t)CC*CC*2;
    u16* wgb  = (u16*)(p);            p += (size_t)CC*CC*2;
    u16* maskbf = (u16*)(p);          p += (size_t)RR*2;        // 288 KiB
    const size_t used = (size_t)(p - ws);
    u16* wagbuf = (ws_size >= used + SZ) ? (u16*)(p) : qbuf;

    kernW<<<dim3(896), dim3(256), 0, stream>>>(w_q, w_k, w_v, w_g, w_o, mask,
        wqb, wkb, wvb, wgb, wob, maskbf);
    kernA<<<dim3(RR/64), dim3(256), 0, stream>>>(pair, ln_w, ln_b, w_bias,
        wqb, wkb, wvb, wgb, qbuf, kbuf, vT, gbuf, biash);
    kernB<<<dim3(768), dim3(256), 0, stream>>>(qbuf, kbuf, vT, gbuf, biash, maskbf, wagbuf);
    kernC<<<dim3(RR/64), dim3(256), 0, stream>>>(wagbuf, wob, out);
}

// Round 12
// 467.369 us; speedup vs baseline: 2.5666x; 1.8201x over previous
//
#include <hip/hip_runtime.h>
#include <hip/hip_bf16.h>

#define NN 384
#define CC 128
#define HH 4
#define DHD 32
#define RR (NN*NN)
#define LN_EPS 1e-5f
#define QSC 0.25503487f          // (1/sqrt(32)) / ln(2)  -> logits in log2 domain
#define LOG2E 1.4426950408889634f
#define NB 3                     // b's per kernB block

typedef unsigned short u16;
typedef __bf16 bf16x8 __attribute__((ext_vector_type(8)));
typedef float f32x4 __attribute__((ext_vector_type(4)));
typedef unsigned short u16x8 __attribute__((ext_vector_type(8)));

__device__ __forceinline__ u16 f2bf(float f) {
    unsigned u = __float_as_uint(f);
    u += 0x7fffu + ((u >> 16) & 1u);        // RNE
    return (u16)(u >> 16);
}
__device__ __forceinline__ float bf2f(u16 s) { return __uint_as_float(((unsigned)s) << 16); }
__device__ __forceinline__ u16 f2h(float f) {
    _Float16 h = (_Float16)f;               // v_cvt_f16_f32 (RNE)
    return __builtin_bit_cast(u16, h);
}
__device__ __forceinline__ float h2f(u16 u) {
    return (float)__builtin_bit_cast(_Float16, u);  // v_cvt_f32_f16
}
__device__ __forceinline__ unsigned cvtpk(float lo, float hi) {
    unsigned r;
    asm("v_cvt_pk_bf16_f32 %0, %1, %2" : "=v"(r) : "v"(lo), "v"(hi));
    return r;
}

// ---------------------------------------------------------------------------
// Kernel W: one-shot converts — 5 weight matrices f32->bf16, mask int32->bf16.
// ---------------------------------------------------------------------------
__global__ __launch_bounds__(256) void kernW(
    const float* __restrict__ wq, const float* __restrict__ wk, const float* __restrict__ wv,
    const float* __restrict__ wg, const float* __restrict__ wo, const int* __restrict__ mask,
    u16* __restrict__ wqb, u16* __restrict__ wkb, u16* __restrict__ wvb,
    u16* __restrict__ wgb, u16* __restrict__ wob, u16* __restrict__ maskbf)
{
    const int idx = blockIdx.x*256 + threadIdx.x;
    if (idx < 5*16384) {
        const int which = idx >> 14, off = idx & 16383;
        const float* src = which==0?wq: which==1?wk: which==2?wv: which==3?wg: wo;
        u16* dst        = which==0?wqb: which==1?wkb: which==2?wvb: which==3?wgb: wob;
        dst[off] = f2bf(src[off]);
    } else {
        const int off = idx - 5*16384;
        if (off < RR) maskbf[off] = (mask[off] != 0) ? (u16)0x3F80 : (u16)0;
    }
}

// ---------------------------------------------------------------------------
// Kernel A: LayerNorm + q/k/v/gate projections + pair bias (fp16, log2 domain).
// q pre-scaled by QSC (softmax scale, log2 domain).
// ---------------------------------------------------------------------------
__global__ __launch_bounds__(256) void kernA(
    const float* __restrict__ pair, const float* __restrict__ ln_w, const float* __restrict__ ln_b,
    const float* __restrict__ w_bias,
    const u16* __restrict__ wqb, const u16* __restrict__ wkb,
    const u16* __restrict__ wvb, const u16* __restrict__ wgb,
    u16* __restrict__ qbuf, u16* __restrict__ kbuf, u16* __restrict__ vT, u16* __restrict__ gbuf,
    u16* __restrict__ biash)
{
    __shared__ __align__(16) u16 x_tile[64*128];   // bf16, pitch 256B, XOR-swizzled
    __shared__ __align__(16) u16 w_lds[128*128];   // bf16, pitch 256B, XOR-swizzled

    const int t = threadIdx.x;
    const int bid = blockIdx.x;
    const int base = bid * 64;
    const int b = base / NN;
    const int m0 = base % NN;

    // ---- LayerNorm: 4 lanes per row ----
    const int rl = t >> 2;
    const int lq = t & 3;
    const int grow = base + rl;
    float x[32];
    {
        const float* src = pair + (size_t)grow * CC + lq * 32;
        #pragma unroll
        for (int j = 0; j < 8; j++) {
            f32x4 v = *reinterpret_cast<const f32x4*>(src + j*4);
            #pragma unroll
            for (int e = 0; e < 4; e++) x[j*4+e] = v[e];
        }
    }
    float s = 0.f, sq = 0.f;
    #pragma unroll
    for (int j = 0; j < 32; j++) { s += x[j]; sq += x[j]*x[j]; }
    s  += __shfl_xor(s, 1);  s  += __shfl_xor(s, 2);
    sq += __shfl_xor(sq, 1); sq += __shfl_xor(sq, 2);
    const float mu = s * (1.f/128.f);
    const float rstd = rsqrtf(sq * (1.f/128.f) - mu*mu + LN_EPS);
    float pb[4] = {0.f,0.f,0.f,0.f};
    #pragma unroll
    for (int j = 0; j < 32; j++) {
        const int c = lq*32 + j;
        float xh = (x[j] - mu) * rstd * ln_w[c] + ln_b[c];
        x[j] = xh;
        #pragma unroll
        for (int h = 0; h < 4; h++) pb[h] += xh * w_bias[h*CC + c];
    }
    #pragma unroll
    for (int j8 = 0; j8 < 4; j8++) {
        u16x8 pk;
        #pragma unroll
        for (int e = 0; e < 8; e++) pk[e] = f2bf(x[j8*8 + e]);
        unsigned addr = (unsigned)(rl*256 + (lq*32 + j8*8)*2) ^ (unsigned)((rl & 7) << 4);
        *reinterpret_cast<u16x8*>(reinterpret_cast<char*>(x_tile) + addr) = pk;
    }
    // pair bias (fp16, log2-domain): bias2[h][q][k] = dot(xhat_k, w_bias[h]) * log2e
    #pragma unroll
    for (int h = 0; h < 4; h++) {
        float v = pb[h];
        v += __shfl_xor(v, 1); v += __shfl_xor(v, 2);
        if (lq == h) biash[h*RR + grow] = f2h(v * LOG2E);
    }

    const int wv = t >> 6;
    const int lane = t & 63;
    const int lc = lane & 15;
    const int kg = lane >> 4;

    bf16x8 afr[4];
    {
        const int rA = wv*16 + lc;
        #pragma unroll
        for (int kt = 0; kt < 4; kt++) {
            unsigned addr = (unsigned)(rA*256 + (kt*32 + kg*8)*2) ^ (unsigned)((rA & 7) << 4);
            afr[kt] = *reinterpret_cast<const bf16x8*>(reinterpret_cast<const char*>(x_tile) + addr);
        }
    }

    const u16* Ws[4] = {wqb, wkb, wvb, wgb};
    for (int wi = 0; wi < 4; wi++) {
        __syncthreads();
        const u16* W = Ws[wi];
        #pragma unroll
        for (int i = 0; i < 8; i++) {
            const int chunk = i*256 + t;
            const int row = chunk >> 4;
            const int colc = (chunk & 15) * 8;
            u16x8 pk = *reinterpret_cast<const u16x8*>(W + row*CC + colc);
            unsigned addr = (unsigned)(row*256 + colc*2) ^ (unsigned)((row & 7) << 4);
            *reinterpret_cast<u16x8*>(reinterpret_cast<char*>(w_lds) + addr) = pk;
        }
        __syncthreads();

        #pragma unroll
        for (int dt = 0; dt < 8; dt++) {
            f32x4 acc = {0.f, 0.f, 0.f, 0.f};
            const int rB = dt*16 + lc;
            #pragma unroll
            for (int kt = 0; kt < 4; kt++) {
                unsigned addr = (unsigned)(rB*256 + (kt*32 + kg*8)*2) ^ (unsigned)((rB & 7) << 4);
                bf16x8 bfr = *reinterpret_cast<const bf16x8*>(reinterpret_cast<const char*>(w_lds) + addr);
                acc = __builtin_amdgcn_mfma_f32_16x16x32_bf16(afr[kt], bfr, acc, 0, 0, 0);
            }
            if (wi == 2) {
                #pragma unroll
                for (int i = 0; i < 4; i++) {
                    const int m = m0 + wv*16 + kg*4 + i;
                    vT[(size_t)(b*CC + dt*16 + lc) * NN + m] = f2bf(acc[i]);
                }
            } else {
                u16* dst = (wi == 0) ? qbuf : (wi == 1) ? kbuf : gbuf;
                #pragma unroll
                for (int i = 0; i < 4; i++) {
                    float v = acc[i];
                    if (wi == 0) v *= QSC;                       // fold softmax scale (log2)
                    if (wi == 3) v = 1.f / (1.f + __expf(-v));   // sigmoid gate
                    dst[(size_t)(base + wv*16 + kg*4 + i) * CC + dt*16 + lc] = f2bf(v);
                }
            }
        }
    }
}

// ---------------------------------------------------------------------------
// Kernel B: attention, FUSED STREAMING (no S[24] array -> live set ~60 VGPR,
// spill-free at any occupancy target the allocator picks). Grid 768 =
// 6 qsplit x 128 bgroup (NB=3). Block = 4 independent waves (no barriers);
// wave owns 16 q-rows. Per (b,h): single pass over 12 key-chunks of 32:
// {QK MFMA x2 (bias as C-in) -> exp2*mask + sum-accum -> cvt_pk -> LDS ->
//  PV MFMA x2 accumulate}. Deferred softmax normalization in epilogue (valid:
// no max-subtraction needed in log2 domain with bounded logits).
// ---------------------------------------------------------------------------
__global__ __launch_bounds__(256) void kernB(
    const u16* __restrict__ qbuf, const u16* __restrict__ kbuf, const u16* __restrict__ vT,
    const u16* __restrict__ gbuf, const u16* __restrict__ biash,
    const u16* __restrict__ maskbf, u16* __restrict__ wagbuf)
{
    __shared__ __align__(16) u16 Plds[4*640];      // per-wave 1280B: PV chunks + epilogue tile

    const int t = threadIdx.x;
    const int w = t >> 6;
    const int lane = t & 63;
    const int lc = lane & 15;
    const int kg = lane >> 4;

    const int bid = blockIdx.x;
    const int qsplit = bid >> 7;       // 0..5  (slow: the 6 sharers of K/V(b) are == mod 8 -> co-XCD)
    const int bgroup = bid & 127;      // 0..127
    const int b0 = bgroup * NB;
    const int qt = qsplit*64 + w*16;   // wave's q-tile

    char* pw = reinterpret_cast<char*>(Plds) + w*1280;
    const unsigned swz = (unsigned)((lc & 3) << 4);

    for (int j = 0; j < NB; j++) {
        const int b = b0 + j;
        for (int h = 0; h < HH; h++) {
            const bf16x8 aq = *reinterpret_cast<const bf16x8*>(
                qbuf + (size_t)(b*NN + qt + lc)*CC + h*DHD + kg*8);

            const u16* bias_base = biash + (size_t)h*RR + (size_t)(qt + lc)*NN + kg*4;
            const u16* k_base    = kbuf + (size_t)(b*NN + lc)*CC + h*DHD + kg*8;
            const u16* m_base    = maskbf + (size_t)b*NN + kg*4;
            const u16* v_base0   = vT + (size_t)(b*CC + h*DHD + lc)*NN + kg*8;
            const u16* v_base1   = vT + (size_t)(b*CC + h*DHD + 16 + lc)*NN + kg*8;

            f32x4 acc0 = {0.f,0.f,0.f,0.f}, acc1 = {0.f,0.f,0.f,0.f};
            f32x4 sum4 = {0.f,0.f,0.f,0.f};

            #pragma unroll
            for (int kt = 0; kt < 12; kt++) {
                // ---- QK^T for 2 m-tiles (32 keys), bias as C-in ----
                const uint2 bu0 = *reinterpret_cast<const uint2*>(bias_base + (2*kt)*16);
                const uint2 bu1 = *reinterpret_cast<const uint2*>(bias_base + (2*kt+1)*16);
                f32x4 cb0, cb1;
                cb0[0] = h2f((u16)(bu0.x & 0xFFFFu));
                cb0[1] = h2f((u16)(bu0.x >> 16));
                cb0[2] = h2f((u16)(bu0.y & 0xFFFFu));
                cb0[3] = h2f((u16)(bu0.y >> 16));
                cb1[0] = h2f((u16)(bu1.x & 0xFFFFu));
                cb1[1] = h2f((u16)(bu1.x >> 16));
                cb1[2] = h2f((u16)(bu1.y & 0xFFFFu));
                cb1[3] = h2f((u16)(bu1.y >> 16));
                const bf16x8 kf0 = *reinterpret_cast<const bf16x8*>(k_base + (size_t)(2*kt)*16*CC);
                const bf16x8 kf1 = *reinterpret_cast<const bf16x8*>(k_base + (size_t)(2*kt+1)*16*CC);
                f32x4 S0 = __builtin_amdgcn_mfma_f32_16x16x32_bf16(kf0, aq, cb0, 0, 0, 0);
                f32x4 S1 = __builtin_amdgcn_mfma_f32_16x16x32_bf16(kf1, aq, cb1, 0, 0, 0);

                // ---- P = exp2(l) * mask01, accumulate sum ----
                const uint2 mp0 = *reinterpret_cast<const uint2*>(m_base + (2*kt)*16);
                const uint2 mp1 = *reinterpret_cast<const uint2*>(m_base + (2*kt+1)*16);
                float m0[4], m1[4];
                m0[0] = __uint_as_float(mp0.x << 16);
                m0[1] = __uint_as_float(mp0.x & 0xFFFF0000u);
                m0[2] = __uint_as_float(mp0.y << 16);
                m0[3] = __uint_as_float(mp0.y & 0xFFFF0000u);
                m1[0] = __uint_as_float(mp1.x << 16);
                m1[1] = __uint_as_float(mp1.x & 0xFFFF0000u);
                m1[2] = __uint_as_float(mp1.y << 16);
                m1[3] = __uint_as_float(mp1.y & 0xFFFF0000u);
                #pragma unroll
                for (int i = 0; i < 4; i++) {
                    float e0 = __builtin_exp2f(S0[i]) * m0[i];
                    float e1 = __builtin_exp2f(S1[i]) * m1[i];
                    S0[i] = e0; S1[i] = e1;
                    sum4[i] += e0 + e1;
                }

                // ---- pack P -> per-wave LDS -> PV A-frag ----
                uint2 w0, w1;
                w0.x = cvtpk(S0[0], S0[1]);
                w0.y = cvtpk(S0[2], S0[3]);
                w1.x = cvtpk(S1[0], S1[1]);
                w1.y = cvtpk(S1[2], S1[3]);
                *reinterpret_cast<uint2*>(pw + ((unsigned)(lc*64 + kg*8)      ^ swz)) = w0;
                *reinterpret_cast<uint2*>(pw + ((unsigned)(lc*64 + 32 + kg*8) ^ swz)) = w1;
                const bf16x8 ap = *reinterpret_cast<const bf16x8*>(
                    pw + ((unsigned)(lc*64 + kg*16) ^ swz));

                // ---- PV accumulate (V frags direct from global vT / L2) ----
                const bf16x8 vf0 = *reinterpret_cast<const bf16x8*>(v_base0 + kt*32);
                const bf16x8 vf1 = *reinterpret_cast<const bf16x8*>(v_base1 + kt*32);
                acc0 = __builtin_amdgcn_mfma_f32_16x16x32_bf16(ap, vf0, acc0, 0, 0, 0);
                acc1 = __builtin_amdgcn_mfma_f32_16x16x32_bf16(ap, vf1, acc1, 0, 0, 0);
            }

            float sums = (sum4[0] + sum4[1]) + (sum4[2] + sum4[3]);
            sums += __shfl_xor(sums, 16);
            sums += __shfl_xor(sums, 32);
            const float sinv = 1.f / sums;

            // epilogue: normalize -> per-wave LDS tile [16 rows][32 cols], pitch 80B
            #pragma unroll
            for (int i = 0; i < 4; i++) {
                const float si = __shfl(sinv, 4*kg + i);
                const int r0 = 4*kg + i;
                *reinterpret_cast<u16*>(pw + r0*80 + lc*2)      = f2bf(acc0[i] * si);
                *reinterpret_cast<u16*>(pw + r0*80 + 32 + lc*2) = f2bf(acc1[i] * si);
            }
            // coalesced readback + gate + 16B stores
            {
                const int rrow = lane >> 2;
                const int ch = lane & 3;
                u16x8 pv8 = *reinterpret_cast<const u16x8*>(pw + rrow*80 + ch*16);
                const size_t grow_ = (size_t)(b*NN + qt + rrow);
                const int gcol = h*DHD + ch*8;
                u16x8 g8 = *reinterpret_cast<const u16x8*>(gbuf + grow_*CC + gcol);
                u16x8 o8;
                #pragma unroll
                for (int e = 0; e < 8; e++) o8[e] = f2bf(bf2f(pv8[e]) * bf2f(g8[e]));
                *reinterpret_cast<u16x8*>(wagbuf + grow_*CC + gcol) = o8;
            }
        }
    }
}

// ---------------------------------------------------------------------------
// Kernel C: out = wag . w_o^T   (streaming GEMM, grid 2304 x 256)
// ---------------------------------------------------------------------------
__global__ __launch_bounds__(256) void kernC(
    const u16* __restrict__ wag, const u16* __restrict__ wob, float* __restrict__ out)
{
    __shared__ __align__(16) u16 a_tile[64*128];

    const int t = threadIdx.x;
    const int base = blockIdx.x * 64;

    {
        const int rl = t >> 2;
        const int lq = t & 3;
        const u16* src = wag + (size_t)(base + rl)*CC + lq*32;
        #pragma unroll
        for (int j8 = 0; j8 < 4; j8++) {
            u16x8 v = *reinterpret_cast<const u16x8*>(src + j8*8);
            unsigned addr = (unsigned)(rl*256 + (lq*32 + j8*8)*2) ^ (unsigned)((rl & 7) << 4);
            *reinterpret_cast<u16x8*>(reinterpret_cast<char*>(a_tile) + addr) = v;
        }
    }
    __syncthreads();

    const int wv = t >> 6;
    const int lane = t & 63;
    const int lc = lane & 15;
    const int kg = lane >> 4;

    bf16x8 afr[4];
    {
        const int rA = wv*16 + lc;
        #pragma unroll
        for (int kt = 0; kt < 4; kt++) {
            unsigned addr = (unsigned)(rA*256 + (kt*32 + kg*8)*2) ^ (unsigned)((rA & 7) << 4);
            afr[kt] = *reinterpret_cast<const bf16x8*>(reinterpret_cast<const char*>(a_tile) + addr);
        }
    }
    #pragma unroll
    for (int et = 0; et < 8; et++) {
        f32x4 acc = {0.f,0.f,0.f,0.f};
        #pragma unroll
        for (int kt = 0; kt < 4; kt++) {
            const bf16x8 bw = *reinterpret_cast<const bf16x8*>(wob + (et*16 + lc)*CC + kt*32 + kg*8);
            acc = __builtin_amdgcn_mfma_f32_16x16x32_bf16(afr[kt], bw, acc, 0, 0, 0);
        }
        #pragma unroll
        for (int i = 0; i < 4; i++)
            out[(size_t)(base + wv*16 + kg*4 + i)*CC + et*16 + lc] = acc[i];
    }
}

extern "C" void kernel_launch(void* const* d_in, const int* in_sizes, int n_in,
                              void* d_out, int out_size, void* d_ws, size_t ws_size,
                              hipStream_t stream)
{
    const float* pair  = (const float*)d_in[0];
    const int*   mask  = (const int*)d_in[1];
    const float* ln_w  = (const float*)d_in[2];
    const float* ln_b  = (const float*)d_in[3];
    const float* w_bias= (const float*)d_in[4];
    const float* w_q   = (const float*)d_in[5];
    const float* w_k   = (const float*)d_in[6];
    const float* w_v   = (const float*)d_in[7];
    const float* w_g   = (const float*)d_in[8];
    const float* w_o   = (const float*)d_in[9];
    float* out = (float*)d_out;

    char* ws = (char*)d_ws;
    const size_t SZ = (size_t)RR * CC * 2;       // 37,748,736
    u16* qbuf = (u16*)(ws);
    u16* kbuf = (u16*)(ws + SZ);
    u16* vT   = (u16*)(ws + 2*SZ);
    u16* gbuf = (u16*)(ws + 3*SZ);
    u16* biash = (u16*)(ws + 4*SZ);                             // 4*RR*2 = 1,179,648
    char* p = ws + 4*SZ + (size_t)4*RR*2;
    u16* wob  = (u16*)(p);            p += (size_t)CC*CC*2;     // 32 KiB
    u16* wqb  = (u16*)(p);            p += (size_t)CC*CC*2;
    u16* wkb  = (u16*)(p);            p += (size_t)CC*CC*2;
    u16* wvb  = (u16*)(p);            p += (size_t)CC*CC*2;
    u16* wgb  = (u16*)(p);            p += (size_t)CC*CC*2;
    u16* maskbf = (u16*)(p);          p += (size_t)RR*2;        // 288 KiB
    const size_t used = (size_t)(p - ws);
    u16* wagbuf = (ws_size >= used + SZ) ? (u16*)(p) : qbuf;

    kernW<<<dim3(896), dim3(256), 0, stream>>>(w_q, w_k, w_v, w_g, w_o, mask,
        wqb, wkb, wvb, wgb, wob, maskbf);
    kernA<<<dim3(RR/64), dim3(256), 0, stream>>>(pair, ln_w, ln_b, w_bias,
        wqb, wkb, wvb, wgb, qbuf, kbuf, vT, gbuf, biash);
    kernB<<<dim3(768), dim3(256), 0, stream>>>(qbuf, kbuf, vT, gbuf, biash, maskbf, wagbuf);
    kernC<<<dim3(RR/64), dim3(256), 0, stream>>>(wagbuf, wob, out);
}